// Round 1
// baseline (146.003 us; speedup 1.0000x reference)
//
#include <hip/hip_runtime.h>

typedef __attribute__((ext_vector_type(8))) short s16x8;
typedef __attribute__((ext_vector_type(4))) float f32x4;
typedef __attribute__((ext_vector_type(16))) float f32x16;
typedef __attribute__((ext_vector_type(2))) unsigned u32x2;
typedef __attribute__((ext_vector_type(4))) unsigned u32x4;

#define MFMA32(a, b, c) __builtin_amdgcn_mfma_f32_16x16x32_bf16((a), (b), (c), 0, 0, 0)

// 32x32x16 bf16 MFMA (gfx950). Host pass may lack the builtin declaration;
// stub it there (never executed on host).
#if __has_builtin(__builtin_amdgcn_mfma_f32_32x32x16_bf16)
#define MFMA3216(a, b, c) __builtin_amdgcn_mfma_f32_32x32x16_bf16((a), (b), (c), 0, 0, 0)
#else
#define MFMA3216(a, b, c) (c) /* host-pass parse stub */
#endif

#if __has_builtin(__builtin_amdgcn_exp2f)
#define EXP2F(x) __builtin_amdgcn_exp2f(x)
#else
#define EXP2F(x) __exp2f(x)
#endif

#if __has_builtin(__builtin_amdgcn_rcpf)
#define RCPF(x) __builtin_amdgcn_rcpf(x)
#else
#define RCPF(x) (1.0f / (x))
#endif

#define SL2E 0.25507313f  // (1/sqrt(32)) * log2(e)

// pack two f32 -> bf16 pair (RNE)
__device__ __forceinline__ unsigned pkrne(float a, float b) {
  unsigned ua = __builtin_bit_cast(unsigned, a);
  unsigned ub = __builtin_bit_cast(unsigned, b);
  ua += 0x7FFFu + ((ua >> 16) & 1u);
  ub += 0x7FFFu + ((ub >> 16) & 1u);
  return __builtin_amdgcn_perm(ub, ua, 0x07060302u);
}

// pack two f32 -> bf16 pair by TRUNCATION (1 v_perm); bias cancels in p/l
// because l is summed from the SAME truncated bf16 values PV consumes.
__device__ __forceinline__ unsigned pktrunc(float a, float b) {
  return __builtin_amdgcn_perm(__builtin_bit_cast(unsigned, b),
                               __builtin_bit_cast(unsigned, a), 0x07060302u);
}

__device__ __forceinline__ unsigned short bfr(float f) {
  unsigned u = __builtin_bit_cast(unsigned, f);
  u += 0x7FFFu + ((u >> 16) & 1u);
  return (unsigned short)(u >> 16);
}

// unpack bf16 pair -> f32
__device__ __forceinline__ float bflo(unsigned u) {
  return __builtin_bit_cast(float, u << 16);
}
__device__ __forceinline__ float bfhi(unsigned u) {
  return __builtin_bit_cast(float, u & 0xFFFF0000u);
}

// v_permlane32_swap_b32: out.x = {a.lo32lanes, b.lo32lanes}, out.y =
// {a.hi32lanes, b.hi32lanes} (exchanges a's upper 32 lanes with b's lower 32).
__device__ __forceinline__ u32x2 plswap(unsigned a, unsigned b) {
#if __has_builtin(__builtin_amdgcn_permlane32_swap)
  return __builtin_amdgcn_permlane32_swap(a, b, false, false);
#else
  unsigned sa = (unsigned)__shfl_xor((int)a, 32, 64);
  unsigned sb = (unsigned)__shfl_xor((int)b, 32, 64);
  bool hi = (threadIdx.x & 63) >= 32;
  u32x2 r;
  r.x = hi ? sb : a;
  r.y = hi ? b : sa;
  return r;
#endif
}

// Async global->LDS: per-lane 16B from g (per-lane addr) lands at
// lds_base + lane*16 (wave-uniform base, lane-linear order).
__device__ __forceinline__ void stage16(const ushort* g, ushort* l, int lane) {
#if __has_builtin(__builtin_amdgcn_global_load_lds)
  __builtin_amdgcn_global_load_lds(
      (__attribute__((address_space(1))) unsigned int*)(unsigned long long)(
          const void*)g,
      (__attribute__((address_space(3))) unsigned int*)(unsigned)(
          unsigned long long)(const void*)l,
      16, 0, 0);
#else
  *(uint4*)(l + lane * 8) = *(const uint4*)g;
#endif
}

// ---------------------------------------------------------------------------
// Prep: transpose+convert fp32 sources into bf16 k-contiguous layouts.
// ---------------------------------------------------------------------------
__global__ __launch_bounds__(256) void prep_kernel(
    const float* __restrict__ x, const float* __restrict__ wqkv,
    const float* __restrict__ wout, ushort* __restrict__ xbf,
    ushort* __restrict__ wT, ushort* __restrict__ woT) {
  const int t = threadIdx.x;
  const int sub = t & 15, grp = t >> 4;
  const int id = blockIdx.x;
  const float* src;
  ushort* dst;
  int src_ld, k0, n0;
  float sc = 1.f;
  if (id < 512) {
    int mt = id & 63, kt = (id >> 6) & 3, b = id >> 8;
    src = x + (size_t)b * 256 * 4096;
    src_ld = 4096;
    dst = xbf + (size_t)b * 4096 * 256;
    k0 = kt * 64;
    n0 = mt * 64;
  } else if (id < 560) {
    int r = id - 512, nt = r % 12, kt = r / 12;
    src = wqkv;
    src_ld = 768;
    dst = wT;
    k0 = kt * 64;
    n0 = nt * 64;
    if (n0 < 256) sc = SL2E;
  } else {
    int r = id - 560, nt = r & 3, kt = r >> 2;
    src = wout;
    src_ld = 256;
    dst = woT;
    k0 = kt * 64;
    n0 = nt * 64;
  }
  const int k = k0 + grp * 4;
  const int n = n0 + sub * 4;
  unsigned d0[4], d1[4];
#pragma unroll
  for (int i = 0; i < 4; ++i) {
    float4 v = *(const float4*)(src + (size_t)(k + i) * src_ld + n);
    d0[i] = pkrne(v.x * sc, v.y * sc);
    d1[i] = pkrne(v.z * sc, v.w * sc);
  }
  u32x2 r0 = {__builtin_amdgcn_perm(d0[1], d0[0], 0x05040100u),
              __builtin_amdgcn_perm(d0[3], d0[2], 0x05040100u)};
  u32x2 r1 = {__builtin_amdgcn_perm(d0[1], d0[0], 0x07060302u),
              __builtin_amdgcn_perm(d0[3], d0[2], 0x07060302u)};
  u32x2 r2 = {__builtin_amdgcn_perm(d1[1], d1[0], 0x05040100u),
              __builtin_amdgcn_perm(d1[3], d1[2], 0x05040100u)};
  u32x2 r3 = {__builtin_amdgcn_perm(d1[1], d1[0], 0x07060302u),
              __builtin_amdgcn_perm(d1[3], d1[2], 0x07060302u)};
  *(u32x2*)(dst + (size_t)(n + 0) * 256 + k) = r0;
  *(u32x2*)(dst + (size_t)(n + 1) * 256 + k) = r1;
  *(u32x2*)(dst + (size_t)(n + 2) * 256 + k) = r2;
  *(u32x2*)(dst + (size_t)(n + 3) * 256 + k) = r3;
}

// ---------------------------------------------------------------------------
// Fused QKV: D[n][tok] = wT(rows n) x xbf(rows tok). (unchanged)
// ---------------------------------------------------------------------------
__global__ __launch_bounds__(256) void qkv_kernel(
    const ushort* __restrict__ xbf, const ushort* __restrict__ wT,
    const float* __restrict__ bq, ushort* __restrict__ QG,
    ushort* __restrict__ KG, ushort* __restrict__ VtG) {
  __shared__ __align__(16) ushort Wl[64][40];
  __shared__ __align__(16) ushort Xl[128][40];
  const int t0 = blockIdx.x * 128;
  const int n0 = blockIdx.y * 64;
  const int t = threadIdx.x;
  const int wid = t >> 6, lane = t & 63;
  const int wy = wid >> 1, wx = wid & 1;
  const int quad = lane >> 4, l16 = lane & 15;
  f32x4 acc[2][4] = {};
  const int wr = t >> 2, wsg = t & 3;
  for (int k0 = 0; k0 < 256; k0 += 32) {
    __syncthreads();
    *(uint4*)&Wl[wr][wsg * 8] =
        *(const uint4*)(wT + (size_t)(n0 + wr) * 256 + k0 + wsg * 8);
#pragma unroll
    for (int i = 0; i < 2; ++i) {
      int fid = t + 256 * i, row = fid >> 2, seg = fid & 3;
      *(uint4*)&Xl[row][seg * 8] =
          *(const uint4*)(xbf + (size_t)(t0 + row) * 256 + k0 + seg * 8);
    }
    __syncthreads();
    s16x8 wf[2], xf[4];
#pragma unroll
    for (int i = 0; i < 2; ++i)
      wf[i] = *(const s16x8*)&Wl[32 * wy + 16 * i + l16][quad * 8];
#pragma unroll
    for (int j = 0; j < 4; ++j)
      xf[j] = *(const s16x8*)&Xl[64 * wx + 16 * j + l16][quad * 8];
#pragma unroll
    for (int i = 0; i < 2; ++i)
#pragma unroll
      for (int j = 0; j < 4; ++j) acc[i][j] = MFMA32(wf[i], xf[j], acc[i][j]);
  }
  if (n0 < 512) {
    ushort* dst = (n0 < 256) ? QG : KG;
    const float bsc = (n0 < 256) ? SL2E : 1.f;
#pragma unroll
    for (int i = 0; i < 2; ++i) {
      int nb = n0 + 32 * wy + 16 * i + 4 * quad;
      float4 b4 = *(const float4*)(bq + nb);
      float bx0 = b4.x * bsc, bx1 = b4.y * bsc, bx2 = b4.z * bsc,
            bx3 = b4.w * bsc;
      int h = ((nb & 255) >> 5);
      int dd0 = nb & 31;
#pragma unroll
      for (int j = 0; j < 4; ++j) {
        int tok = t0 + 64 * wx + 16 * j + l16;
        int b = tok >> 12, tokn = tok & 4095;
        u32x2 pk = {pkrne(acc[i][j][0] + bx0, acc[i][j][1] + bx1),
                    pkrne(acc[i][j][2] + bx2, acc[i][j][3] + bx3)};
        *(u32x2*)(dst + ((size_t)(b * 8 + h) * 4096 + tokn) * 32 + dd0) = pk;
      }
    }
  } else {
#pragma unroll
    for (int i = 0; i < 2; ++i) {
      int nb = n0 + 32 * wy + 16 * i + 4 * quad;
      float4 b4 = *(const float4*)(bq + nb);
      float bb[4] = {b4.x, b4.y, b4.z, b4.w};
#pragma unroll
      for (int r = 0; r < 4; ++r) {
        int nn = nb + r - 512;
        int h = nn >> 5, ddv = nn & 31;
        ushort* vrow = VtG + (size_t)(h * 32 + ddv) * 4096;
#pragma unroll
        for (int j = 0; j < 4; ++j) {
          int tok = t0 + 64 * wx + 16 * j + l16;
          int b = tok >> 12, tokn = tok & 4095;
          vrow[(size_t)b * 8 * 32 * 4096 + tokn] = bfr(acc[i][j][r] + bb[r]);
        }
      }
    }
  }
}

// ---------------------------------------------------------------------------
// Flash attention, SPLIT-K x3, 32x32 MFMA path.
//
// Per wave: 32 q-rows, k-loop in 64-k steps of two 32x32 score tiles.
//  QK^T: S = mfma_32x32x16(K, Q) accumulated over the 2 dk-halves.
//        C layout: col = q = lane&31, row = k = (r&3)+8*(r>>2)+4*hi.
//  Softmax: exp2 in-register (Q pre-scaled by SL2E), truncate-pack to bf16.
//        l accumulated on VALU from the SAME truncated bf16 values PV
//        consumes (exactly the old ones-MFMA semantics, zero MFMA cost).
//        P redistributed to the PV A-operand layout (A[q][k=8*hi+e]) with
//        4 v_permlane32_swap per tile: swap(A0,B0)->(w0,w2), swap(A1,B1)->
//        (w1,w3) per k-half.
//  PV:   o = mfma_32x32x16(P, V); output C: row = q(crow), col = d = lane&31.
//
// LDS is FRAGMENT-LINEAR: K chunk [s][h][hi][k][8e] and V chunk
// [s][h][hi][d][8e], 1KB per (s,h) chunk, so every ds_read_b128 is
// base + lane*16 (zero bank conflicts) and staging is plain
// global_load_lds width-16 (wave-uniform dest, lane-linear). Wave w stages
// chunk (s,h) = (w>>1, w&1) of both K and V. 16 KiB LDS, double-buffered,
// one barrier per 64-k step (m97 pattern).
// ---------------------------------------------------------------------------
__global__ __launch_bounds__(256, 4) void attn_split(
    const ushort* __restrict__ QG, const ushort* __restrict__ KG,
    const ushort* __restrict__ VtG, ushort* __restrict__ OF0,
    ushort* __restrict__ OFb, float* __restrict__ LF) {
  __shared__ __align__(64) ushort KVs[2][4096];  // per buf: K 2048, V 2048
  const int id = blockIdx.x;
  const int bh = (id & 7) * 2 + ((id >> 3) & 1);  // XCD-affine heads
  const int q0 = ((id >> 4) & 31) * 128;
  const int sp = id >> 9;                           // split index 0..2
  const int kt0 = (sp * 64 + 2) / 3;                // {0,22,43}
  const int niter = ((sp + 1) * 64 + 2) / 3 - kt0;  // {22,21,21}
  const int t = threadIdx.x;
  const int wid = t >> 6, lane = t & 63;
  const int l5 = lane & 31, hi = lane >> 5;
  const size_t base = (size_t)bh * 4096 * 32;
  const ushort* qp = QG + base;
  const ushort* kp = KG + base;
  const ushort* vp = VtG + base;
  const int qw = q0 + 32 * wid;
  // Q fragments (held in regs): B[dk = h*16 + hi*8 + e][q = l5]
  const ushort* qrow = qp + (size_t)(qw + l5) * 32 + hi * 8;
  const s16x8 qf0 = *(const s16x8*)(qrow);
  const s16x8 qf1 = *(const s16x8*)(qrow + 16);
  // Staging assignment: wave wid -> chunk (s,h)
  const int sK = wid >> 1, hK = wid & 1;
  const int kdst = sK * 1024 + hK * 512;  // ushort offset of 1KB chunk
  const ushort* kpre =
      kp + (size_t)(kt0 * 64 + sK * 32 + l5) * 32 + hK * 16 + hi * 8;
  const ushort* vpre =
      vp + (size_t)l5 * 4096 + kt0 * 64 + sK * 32 + hK * 16 + hi * 8;
  stage16(kpre, &KVs[0][kdst], lane);
  stage16(vpre, &KVs[0][2048 + kdst], lane);
  kpre += 2048;  // next 64-k tile: +64 tokens * 32 dd
  vpre += 64;    // next 64-k tile: +64 tokens
  __syncthreads();
  f32x16 o = {};
  float lacc = 0.f;
  for (int i = 0; i < niter; ++i) {
    const int cur = i & 1;
    if (i + 1 < niter) {
      stage16(kpre, &KVs[cur ^ 1][kdst], lane);
      stage16(vpre, &KVs[cur ^ 1][2048 + kdst], lane);
      kpre += 2048;
      vpre += 64;
    }
    const ushort* kb = &KVs[cur][0];
    const ushort* vb = &KVs[cur][2048];
#pragma unroll
    for (int s = 0; s < 2; ++s) {
      const s16x8 ka0 = *(const s16x8*)(kb + s * 1024 + lane * 8);
      const s16x8 ka1 = *(const s16x8*)(kb + s * 1024 + 512 + lane * 8);
      f32x16 S = {};
      S = MFMA3216(ka0, qf0, S);
      S = MFMA3216(ka1, qf1, S);
      unsigned w8[8];
#pragma unroll
      for (int ii = 0; ii < 8; ++ii)
        w8[ii] = pktrunc(EXP2F(S[2 * ii]), EXP2F(S[2 * ii + 1]));
      // l from the truncated values (bias cancels exactly as before)
#pragma unroll
      for (int ii = 0; ii < 8; ++ii) lacc += bflo(w8[ii]) + bfhi(w8[ii]);
      // Redistribute to PV A-operand layout: A[q][k = 8*hi + e] per k-half.
      u32x2 sw0 = plswap(w8[0], w8[2]);
      u32x2 sw1 = plswap(w8[1], w8[3]);
      u32x2 sw2 = plswap(w8[4], w8[6]);
      u32x2 sw3 = plswap(w8[5], w8[7]);
      u32x4 pa0 = {sw0.x, sw1.x, sw0.y, sw1.y};  // k 0..15 of subtile
      u32x4 pa1 = {sw2.x, sw3.x, sw2.y, sw3.y};  // k 16..31
      const s16x8 va0 = *(const s16x8*)(vb + s * 1024 + lane * 8);
      const s16x8 va1 = *(const s16x8*)(vb + s * 1024 + 512 + lane * 8);
      o = MFMA3216(__builtin_bit_cast(s16x8, pa0), va0, o);
      o = MFMA3216(__builtin_bit_cast(s16x8, pa1), va1, o);
    }
    __syncthreads();
  }
  // Store un-normalized bf16 partial O + f32 partial l.
  ushort* OFs = (sp == 0) ? OF0 : OFb + (size_t)(sp - 1) * 2097152;
  float* LFs = LF + (size_t)sp * 65536;
#pragma unroll
  for (int r = 0; r < 16; ++r) {
    int q = qw + (r & 3) + 8 * (r >> 2) + 4 * hi;
    OFs[((size_t)bh * 4096 + q) * 32 + l5] = bfr(o[r]);
  }
  float lw = lacc + __shfl_xor(lacc, 32, 64);
  if (lane < 32) LFs[(size_t)bh * 4096 + qw + lane] = lw;
}

// ---------------------------------------------------------------------------
// Out-proj with fused 3-way split-combine + normalization in the staging.
// ---------------------------------------------------------------------------
__global__ __launch_bounds__(256) void proj_split(
    const ushort* __restrict__ OF0, const ushort* __restrict__ OFb,
    const float* __restrict__ LF, const ushort* __restrict__ woT,
    const float* __restrict__ bo, float* __restrict__ out) {
  __shared__ __align__(16) ushort Wl[64][40];
  __shared__ __align__(16) ushort Xl[128][40];
  const int t0 = blockIdx.x * 128;
  const int c0 = blockIdx.y * 64;
  const int t = threadIdx.x;
  const int wid = t >> 6, lane = t & 63;
  const int wy = wid >> 1, wx = wid & 1;
  const int quad = lane >> 4, l16 = lane & 15;
  f32x4 acc[2][4] = {};
  const int wr = t >> 2, wsg = t & 3;
  const int c8 = (t & 7) * 4;  // dd column (4 ushorts)
  for (int k0 = 0; k0 < 256; k0 += 32) {
    __syncthreads();
    *(uint4*)&Wl[wr][wsg * 8] =
        *(const uint4*)(woT + (size_t)(c0 + wr) * 256 + k0 + wsg * 8);
    const int hh = k0 >> 5;
#pragma unroll
    for (int p = 0; p < 4; ++p) {
      int row = 32 * p + (t >> 3);
      int tok = t0 + row, bb = tok >> 12, tokn = tok & 4095;
      size_t ro = (size_t)(bb * 8 + hh) * 4096 + tokn;
      size_t oi = ro * 32 + c8;
      uint2 a0 = *(const uint2*)(OF0 + oi);
      uint2 a1 = *(const uint2*)(OFb + oi);
      uint2 a2 = *(const uint2*)(OFb + 2097152 + oi);
      float l = LF[ro] + LF[65536 + ro] + LF[131072 + ro];
      float inv = RCPF(l);
      f32x4 s;
      s[0] = bflo(a0.x) + bflo(a1.x) + bflo(a2.x);
      s[1] = bfhi(a0.x) + bfhi(a1.x) + bfhi(a2.x);
      s[2] = bflo(a0.y) + bflo(a1.y) + bflo(a2.y);
      s[3] = bfhi(a0.y) + bfhi(a1.y) + bfhi(a2.y);
      s *= inv;
      u32x2 pk = {pkrne(s[0], s[1]), pkrne(s[2], s[3])};
      *(u32x2*)&Xl[row][c8] = pk;
    }
    __syncthreads();
    s16x8 wf[2], xf[4];
#pragma unroll
    for (int i = 0; i < 2; ++i)
      wf[i] = *(const s16x8*)&Wl[32 * wy + 16 * i + l16][quad * 8];
#pragma unroll
    for (int j = 0; j < 4; ++j)
      xf[j] = *(const s16x8*)&Xl[64 * wx + 16 * j + l16][quad * 8];
#pragma unroll
    for (int i = 0; i < 2; ++i)
#pragma unroll
      for (int j = 0; j < 4; ++j) acc[i][j] = MFMA32(wf[i], xf[j], acc[i][j]);
  }
#pragma unroll
  for (int i = 0; i < 2; ++i) {
    int cb = c0 + 32 * wy + 16 * i + 4 * quad;
    float4 b4 = *(const float4*)(bo + cb);
    float bb[4] = {b4.x, b4.y, b4.z, b4.w};
#pragma unroll
    for (int j = 0; j < 4; ++j) {
      int tok = t0 + 64 * wx + 16 * j + l16;
      int b = tok >> 12, tokn = tok & 4095;
#pragma unroll
      for (int r = 0; r < 4; ++r)
        out[((size_t)(b * 256 + cb + r)) * 4096 + tokn] = acc[i][j][r] + bb[r];
    }
  }
}

extern "C" void kernel_launch(void* const* d_in, const int* in_sizes, int n_in,
                              void* d_out, int out_size, void* d_ws, size_t ws_size,
                              hipStream_t stream) {
  (void)in_sizes; (void)n_in; (void)out_size; (void)ws_size;
  const float* x = (const float*)d_in[0];
  const float* wq = (const float*)d_in[1];
  const float* bq = (const float*)d_in[2];
  const float* wo = (const float*)d_in[3];
  const float* bo = (const float*)d_in[4];
  float* out = (float*)d_out;
  ushort* ws = (ushort*)d_ws;
  // ws layout (26.5 MB used; ws_size >= 30.9 MB verified rounds 7-8):
  ushort* xbf = ws;                    // [8192][256]  (dead after qkv)
  ushort* OF0 = ws;                    // split0 partial O overlays dead xbf
  ushort* QG  = ws + 2097152;          // [2][8][4096][32]
  ushort* KG  = ws + 4194304;
  ushort* VtG = ws + 6291456;          // [2][8][32][4096]
  ushort* wT  = ws + 8388608;          // [768][256]
  ushort* woT = ws + 8585216;          // [256][256]
  ushort* OFb = ws + 8650752;          // splits 1,2: 2 x 2,097,152 ushorts
  float* LF = (float*)(ws + 12845056); // [3][16][4096] f32
  prep_kernel<<<576, 256, 0, stream>>>(x, wq, wo, xbf, wT, woT);
  qkv_kernel<<<dim3(64, 12), 256, 0, stream>>>(xbf, wT, bq, QG, KG, VtG);
  attn_split<<<1536, 256, 0, stream>>>(QG, KG, VtG, OF0, OFb, LF);
  proj_split<<<dim3(64, 4), 256, 0, stream>>>(OF0, OFb, LF, woT, bo, out);
}

// Round 2
// 139.653 us; speedup vs baseline: 1.0455x; 1.0455x over previous
//
#include <hip/hip_runtime.h>

typedef __attribute__((ext_vector_type(8))) short s16x8;
typedef __attribute__((ext_vector_type(4))) float f32x4;
typedef __attribute__((ext_vector_type(16))) float f32x16;
typedef __attribute__((ext_vector_type(2))) unsigned u32x2;
typedef __attribute__((ext_vector_type(4))) unsigned u32x4;

#define MFMA32(a, b, c) __builtin_amdgcn_mfma_f32_16x16x32_bf16((a), (b), (c), 0, 0, 0)

// 32x32x16 bf16 MFMA (gfx950). Host pass may lack the builtin declaration;
// stub it there (never executed on host).
#if __has_builtin(__builtin_amdgcn_mfma_f32_32x32x16_bf16)
#define MFMA3216(a, b, c) __builtin_amdgcn_mfma_f32_32x32x16_bf16((a), (b), (c), 0, 0, 0)
#else
#define MFMA3216(a, b, c) (c) /* host-pass parse stub */
#endif

#if __has_builtin(__builtin_amdgcn_exp2f)
#define EXP2F(x) __builtin_amdgcn_exp2f(x)
#else
#define EXP2F(x) __exp2f(x)
#endif

#if __has_builtin(__builtin_amdgcn_rcpf)
#define RCPF(x) __builtin_amdgcn_rcpf(x)
#else
#define RCPF(x) (1.0f / (x))
#endif

#define SL2E 0.25507313f  // (1/sqrt(32)) * log2(e)

// pack two f32 -> bf16 pair (RNE)
__device__ __forceinline__ unsigned pkrne(float a, float b) {
  unsigned ua = __builtin_bit_cast(unsigned, a);
  unsigned ub = __builtin_bit_cast(unsigned, b);
  ua += 0x7FFFu + ((ua >> 16) & 1u);
  ub += 0x7FFFu + ((ub >> 16) & 1u);
  return __builtin_amdgcn_perm(ub, ua, 0x07060302u);
}

// pack two f32 -> bf16 pair by TRUNCATION (1 v_perm); bias cancels in p/l
// because l is accumulated (ones-B MFMA) from the SAME truncated bf16
// values PV consumes.
__device__ __forceinline__ unsigned pktrunc(float a, float b) {
  return __builtin_amdgcn_perm(__builtin_bit_cast(unsigned, b),
                               __builtin_bit_cast(unsigned, a), 0x07060302u);
}

__device__ __forceinline__ unsigned short bfr(float f) {
  unsigned u = __builtin_bit_cast(unsigned, f);
  u += 0x7FFFu + ((u >> 16) & 1u);
  return (unsigned short)(u >> 16);
}

// unpack bf16 pair -> f32
__device__ __forceinline__ float bflo(unsigned u) {
  return __builtin_bit_cast(float, u << 16);
}
__device__ __forceinline__ float bfhi(unsigned u) {
  return __builtin_bit_cast(float, u & 0xFFFF0000u);
}

// v_permlane32_swap_b32: out.x = {a.lo32lanes, b.lo32lanes}, out.y =
// {a.hi32lanes, b.hi32lanes} (exchanges a's upper 32 lanes with b's lower 32).
__device__ __forceinline__ u32x2 plswap(unsigned a, unsigned b) {
#if __has_builtin(__builtin_amdgcn_permlane32_swap)
  return __builtin_amdgcn_permlane32_swap(a, b, false, false);
#else
  unsigned sa = (unsigned)__shfl_xor((int)a, 32, 64);
  unsigned sb = (unsigned)__shfl_xor((int)b, 32, 64);
  bool hi = (threadIdx.x & 63) >= 32;
  u32x2 r;
  r.x = hi ? sb : a;
  r.y = hi ? b : sa;
  return r;
#endif
}

// Async global->LDS: per-lane 16B from g (per-lane addr) lands at
// lds_base + lane*16 (wave-uniform base, lane-linear order).
__device__ __forceinline__ void stage16(const ushort* g, ushort* l, int lane) {
#if __has_builtin(__builtin_amdgcn_global_load_lds)
  __builtin_amdgcn_global_load_lds(
      (__attribute__((address_space(1))) unsigned int*)(unsigned long long)(
          const void*)g,
      (__attribute__((address_space(3))) unsigned int*)(unsigned)(
          unsigned long long)(const void*)l,
      16, 0, 0);
#else
  *(uint4*)(l + lane * 8) = *(const uint4*)g;
#endif
}

// ---------------------------------------------------------------------------
// Prep: transpose+convert fp32 sources into bf16 k-contiguous layouts.
// ---------------------------------------------------------------------------
__global__ __launch_bounds__(256) void prep_kernel(
    const float* __restrict__ x, const float* __restrict__ wqkv,
    const float* __restrict__ wout, ushort* __restrict__ xbf,
    ushort* __restrict__ wT, ushort* __restrict__ woT) {
  const int t = threadIdx.x;
  const int sub = t & 15, grp = t >> 4;
  const int id = blockIdx.x;
  const float* src;
  ushort* dst;
  int src_ld, k0, n0;
  float sc = 1.f;
  if (id < 512) {
    int mt = id & 63, kt = (id >> 6) & 3, b = id >> 8;
    src = x + (size_t)b * 256 * 4096;
    src_ld = 4096;
    dst = xbf + (size_t)b * 4096 * 256;
    k0 = kt * 64;
    n0 = mt * 64;
  } else if (id < 560) {
    int r = id - 512, nt = r % 12, kt = r / 12;
    src = wqkv;
    src_ld = 768;
    dst = wT;
    k0 = kt * 64;
    n0 = nt * 64;
    if (n0 < 256) sc = SL2E;
  } else {
    int r = id - 560, nt = r & 3, kt = r >> 2;
    src = wout;
    src_ld = 256;
    dst = woT;
    k0 = kt * 64;
    n0 = nt * 64;
  }
  const int k = k0 + grp * 4;
  const int n = n0 + sub * 4;
  unsigned d0[4], d1[4];
#pragma unroll
  for (int i = 0; i < 4; ++i) {
    float4 v = *(const float4*)(src + (size_t)(k + i) * src_ld + n);
    d0[i] = pkrne(v.x * sc, v.y * sc);
    d1[i] = pkrne(v.z * sc, v.w * sc);
  }
  u32x2 r0 = {__builtin_amdgcn_perm(d0[1], d0[0], 0x05040100u),
              __builtin_amdgcn_perm(d0[3], d0[2], 0x05040100u)};
  u32x2 r1 = {__builtin_amdgcn_perm(d0[1], d0[0], 0x07060302u),
              __builtin_amdgcn_perm(d0[3], d0[2], 0x07060302u)};
  u32x2 r2 = {__builtin_amdgcn_perm(d1[1], d1[0], 0x05040100u),
              __builtin_amdgcn_perm(d1[3], d1[2], 0x05040100u)};
  u32x2 r3 = {__builtin_amdgcn_perm(d1[1], d1[0], 0x07060302u),
              __builtin_amdgcn_perm(d1[3], d1[2], 0x07060302u)};
  *(u32x2*)(dst + (size_t)(n + 0) * 256 + k) = r0;
  *(u32x2*)(dst + (size_t)(n + 1) * 256 + k) = r1;
  *(u32x2*)(dst + (size_t)(n + 2) * 256 + k) = r2;
  *(u32x2*)(dst + (size_t)(n + 3) * 256 + k) = r3;
}

// ---------------------------------------------------------------------------
// Fused QKV: D[n][tok] = wT(rows n) x xbf(rows tok). (unchanged)
// ---------------------------------------------------------------------------
__global__ __launch_bounds__(256) void qkv_kernel(
    const ushort* __restrict__ xbf, const ushort* __restrict__ wT,
    const float* __restrict__ bq, ushort* __restrict__ QG,
    ushort* __restrict__ KG, ushort* __restrict__ VtG) {
  __shared__ __align__(16) ushort Wl[64][40];
  __shared__ __align__(16) ushort Xl[128][40];
  const int t0 = blockIdx.x * 128;
  const int n0 = blockIdx.y * 64;
  const int t = threadIdx.x;
  const int wid = t >> 6, lane = t & 63;
  const int wy = wid >> 1, wx = wid & 1;
  const int quad = lane >> 4, l16 = lane & 15;
  f32x4 acc[2][4] = {};
  const int wr = t >> 2, wsg = t & 3;
  for (int k0 = 0; k0 < 256; k0 += 32) {
    __syncthreads();
    *(uint4*)&Wl[wr][wsg * 8] =
        *(const uint4*)(wT + (size_t)(n0 + wr) * 256 + k0 + wsg * 8);
#pragma unroll
    for (int i = 0; i < 2; ++i) {
      int fid = t + 256 * i, row = fid >> 2, seg = fid & 3;
      *(uint4*)&Xl[row][seg * 8] =
          *(const uint4*)(xbf + (size_t)(t0 + row) * 256 + k0 + seg * 8);
    }
    __syncthreads();
    s16x8 wf[2], xf[4];
#pragma unroll
    for (int i = 0; i < 2; ++i)
      wf[i] = *(const s16x8*)&Wl[32 * wy + 16 * i + l16][quad * 8];
#pragma unroll
    for (int j = 0; j < 4; ++j)
      xf[j] = *(const s16x8*)&Xl[64 * wx + 16 * j + l16][quad * 8];
#pragma unroll
    for (int i = 0; i < 2; ++i)
#pragma unroll
      for (int j = 0; j < 4; ++j) acc[i][j] = MFMA32(wf[i], xf[j], acc[i][j]);
  }
  if (n0 < 512) {
    ushort* dst = (n0 < 256) ? QG : KG;
    const float bsc = (n0 < 256) ? SL2E : 1.f;
#pragma unroll
    for (int i = 0; i < 2; ++i) {
      int nb = n0 + 32 * wy + 16 * i + 4 * quad;
      float4 b4 = *(const float4*)(bq + nb);
      float bx0 = b4.x * bsc, bx1 = b4.y * bsc, bx2 = b4.z * bsc,
            bx3 = b4.w * bsc;
      int h = ((nb & 255) >> 5);
      int dd0 = nb & 31;
#pragma unroll
      for (int j = 0; j < 4; ++j) {
        int tok = t0 + 64 * wx + 16 * j + l16;
        int b = tok >> 12, tokn = tok & 4095;
        u32x2 pk = {pkrne(acc[i][j][0] + bx0, acc[i][j][1] + bx1),
                    pkrne(acc[i][j][2] + bx2, acc[i][j][3] + bx3)};
        *(u32x2*)(dst + ((size_t)(b * 8 + h) * 4096 + tokn) * 32 + dd0) = pk;
      }
    }
  } else {
#pragma unroll
    for (int i = 0; i < 2; ++i) {
      int nb = n0 + 32 * wy + 16 * i + 4 * quad;
      float4 b4 = *(const float4*)(bq + nb);
      float bb[4] = {b4.x, b4.y, b4.z, b4.w};
#pragma unroll
      for (int r = 0; r < 4; ++r) {
        int nn = nb + r - 512;
        int h = nn >> 5, ddv = nn & 31;
        ushort* vrow = VtG + (size_t)(h * 32 + ddv) * 4096;
#pragma unroll
        for (int j = 0; j < 4; ++j) {
          int tok = t0 + 64 * wx + 16 * j + l16;
          int b = tok >> 12, tokn = tok & 4095;
          vrow[(size_t)b * 8 * 32 * 4096 + tokn] = bfr(acc[i][j][r] + bb[r]);
        }
      }
    }
  }
}

// ---------------------------------------------------------------------------
// Flash attention, SPLIT-K x2, 32x32 MFMA path.
//
// Grid 1024 = exactly 4 blocks/CU; __launch_bounds__(256,4) caps the unified
// reg budget at 128 (fits: o/o_l 32 acc + S 16 + fragments ~60) so all 4
// blocks are resident -> zero tail, 16 waves/CU.
//
// Per wave: 32 q-rows, k-loop in 64-k steps of two 32x32 score tiles.
//  QK^T: S = mfma_32x32x16(K, Q) over the 2 dk-halves.
//        C layout: col = q = lane&31, row = k = (r&3)+8*(r>>2)+4*hi.
//  Softmax: exp2 in-register (Q pre-scaled by SL2E), truncate-pack to bf16,
//        redistribute to PV A-layout with 4 v_permlane32_swap per tile.
//  l:    ones-B MFMA on the SAME packed P fragments PV consumes
//        (o_l[q][*] = sum_k P[q][k]; truncation bias cancels in O/l).
//        Keeps l off the binding VALU pipe (round-1 lesson: VALU lacc
//        cost +11us).
//  PV:   o = mfma_32x32x16(P, V); C: row = q(crow), col = d = lane&31.
//
// LDS fragment-linear, ds_read = base + lane*16 (zero bank conflicts),
// staging via global_load_lds width-16. 16 KiB LDS, double-buffered,
// one barrier per 64-k step.
// ---------------------------------------------------------------------------
__global__ __launch_bounds__(256, 4) void attn_split(
    const ushort* __restrict__ QG, const ushort* __restrict__ KG,
    const ushort* __restrict__ VtG, ushort* __restrict__ OF0,
    ushort* __restrict__ OFb, float* __restrict__ LF) {
  __shared__ __align__(64) ushort KVs[2][4096];  // per buf: K 2048, V 2048
  const int id = blockIdx.x;
  const int bh = (id & 7) * 2 + ((id >> 3) & 1);  // XCD-affine heads
  const int q0 = ((id >> 4) & 31) * 128;
  const int sp = id >> 9;      // split index 0..1
  const int kt0 = sp * 32;     // 32 k-tiles (of 64 tokens) per split
  const int niter = 32;
  const int t = threadIdx.x;
  const int wid = t >> 6, lane = t & 63;
  const int l5 = lane & 31, hi = lane >> 5;
  const size_t base = (size_t)bh * 4096 * 32;
  const ushort* qp = QG + base;
  const ushort* kp = KG + base;
  const ushort* vp = VtG + base;
  const int qw = q0 + 32 * wid;
  // Q fragments (held in regs): B[dk = h*16 + hi*8 + e][q = l5]
  const ushort* qrow = qp + (size_t)(qw + l5) * 32 + hi * 8;
  const s16x8 qf0 = *(const s16x8*)(qrow);
  const s16x8 qf1 = *(const s16x8*)(qrow + 16);
  // Staging assignment: wave wid -> chunk (s,h)
  const int sK = wid >> 1, hK = wid & 1;
  const int kdst = sK * 1024 + hK * 512;  // ushort offset of 1KB chunk
  const ushort* kpre =
      kp + (size_t)(kt0 * 64 + sK * 32 + l5) * 32 + hK * 16 + hi * 8;
  const ushort* vpre =
      vp + (size_t)l5 * 4096 + kt0 * 64 + sK * 32 + hK * 16 + hi * 8;
  stage16(kpre, &KVs[0][kdst], lane);
  stage16(vpre, &KVs[0][2048 + kdst], lane);
  kpre += 2048;  // next 64-k tile: +64 tokens * 32 dd
  vpre += 64;    // next 64-k tile: +64 tokens
  __syncthreads();
  f32x16 o = {};
  f32x16 o_l = {};
  const s16x8 ones8 = {(short)0x3F80, (short)0x3F80, (short)0x3F80,
                       (short)0x3F80, (short)0x3F80, (short)0x3F80,
                       (short)0x3F80, (short)0x3F80};
  for (int i = 0; i < niter; ++i) {
    const int cur = i & 1;
    if (i + 1 < niter) {
      stage16(kpre, &KVs[cur ^ 1][kdst], lane);
      stage16(vpre, &KVs[cur ^ 1][2048 + kdst], lane);
      kpre += 2048;
      vpre += 64;
    }
    const ushort* kb = &KVs[cur][0];
    const ushort* vb = &KVs[cur][2048];
#pragma unroll
    for (int s = 0; s < 2; ++s) {
      const s16x8 ka0 = *(const s16x8*)(kb + s * 1024 + lane * 8);
      const s16x8 ka1 = *(const s16x8*)(kb + s * 1024 + 512 + lane * 8);
      f32x16 S = {};
      S = MFMA3216(ka0, qf0, S);
      S = MFMA3216(ka1, qf1, S);
      unsigned w8[8];
#pragma unroll
      for (int ii = 0; ii < 8; ++ii)
        w8[ii] = pktrunc(EXP2F(S[2 * ii]), EXP2F(S[2 * ii + 1]));
      // Redistribute to PV A-operand layout: A[q][k = 8*hi + e] per k-half.
      u32x2 sw0 = plswap(w8[0], w8[2]);
      u32x2 sw1 = plswap(w8[1], w8[3]);
      u32x2 sw2 = plswap(w8[4], w8[6]);
      u32x2 sw3 = plswap(w8[5], w8[7]);
      u32x4 pa0 = {sw0.x, sw1.x, sw0.y, sw1.y};  // k 0..15 of subtile
      u32x4 pa1 = {sw2.x, sw3.x, sw2.y, sw3.y};  // k 16..31
      const s16x8 pA0 = __builtin_bit_cast(s16x8, pa0);
      const s16x8 pA1 = __builtin_bit_cast(s16x8, pa1);
      const s16x8 va0 = *(const s16x8*)(vb + s * 1024 + lane * 8);
      const s16x8 va1 = *(const s16x8*)(vb + s * 1024 + 512 + lane * 8);
      o = MFMA3216(pA0, va0, o);
      o = MFMA3216(pA1, va1, o);
      // l on the MFMA pipe (idle headroom), same truncated P values.
      o_l = MFMA3216(pA0, ones8, o_l);
      o_l = MFMA3216(pA1, ones8, o_l);
    }
    __syncthreads();
  }
  // Store un-normalized bf16 partial O + f32 partial l.
  ushort* OFs = (sp == 0) ? OF0 : OFb;
  float* LFs = LF + (size_t)sp * 65536;
#pragma unroll
  for (int r = 0; r < 16; ++r) {
    int q = qw + (r & 3) + 8 * (r >> 2) + 4 * hi;
    OFs[((size_t)bh * 4096 + q) * 32 + l5] = bfr(o[r]);
  }
  // o_l: C[row=q][col=d] with l[q] replicated across d. Lane (l5,hi) holds
  // rows crow(r,hi); let lanes l5<16 each store row r=l5 of their hi-half.
  float lval = o_l[0];
#pragma unroll
  for (int r = 1; r < 16; ++r) lval = (l5 == r) ? o_l[r] : lval;
  if (l5 < 16)
    LFs[(size_t)bh * 4096 + qw + (l5 & 3) + 8 * (l5 >> 2) + 4 * hi] = lval;
}

// ---------------------------------------------------------------------------
// Out-proj with fused 2-way split-combine + normalization in the staging.
// ---------------------------------------------------------------------------
__global__ __launch_bounds__(256) void proj_split(
    const ushort* __restrict__ OF0, const ushort* __restrict__ OFb,
    const float* __restrict__ LF, const ushort* __restrict__ woT,
    const float* __restrict__ bo, float* __restrict__ out) {
  __shared__ __align__(16) ushort Wl[64][40];
  __shared__ __align__(16) ushort Xl[128][40];
  const int t0 = blockIdx.x * 128;
  const int c0 = blockIdx.y * 64;
  const int t = threadIdx.x;
  const int wid = t >> 6, lane = t & 63;
  const int wy = wid >> 1, wx = wid & 1;
  const int quad = lane >> 4, l16 = lane & 15;
  f32x4 acc[2][4] = {};
  const int wr = t >> 2, wsg = t & 3;
  const int c8 = (t & 7) * 4;  // dd column (4 ushorts)
  for (int k0 = 0; k0 < 256; k0 += 32) {
    __syncthreads();
    *(uint4*)&Wl[wr][wsg * 8] =
        *(const uint4*)(woT + (size_t)(c0 + wr) * 256 + k0 + wsg * 8);
    const int hh = k0 >> 5;
#pragma unroll
    for (int p = 0; p < 4; ++p) {
      int row = 32 * p + (t >> 3);
      int tok = t0 + row, bb = tok >> 12, tokn = tok & 4095;
      size_t ro = (size_t)(bb * 8 + hh) * 4096 + tokn;
      size_t oi = ro * 32 + c8;
      uint2 a0 = *(const uint2*)(OF0 + oi);
      uint2 a1 = *(const uint2*)(OFb + oi);
      float l = LF[ro] + LF[65536 + ro];
      float inv = RCPF(l);
      f32x4 s;
      s[0] = bflo(a0.x) + bflo(a1.x);
      s[1] = bfhi(a0.x) + bfhi(a1.x);
      s[2] = bflo(a0.y) + bflo(a1.y);
      s[3] = bfhi(a0.y) + bfhi(a1.y);
      s *= inv;
      u32x2 pk = {pkrne(s[0], s[1]), pkrne(s[2], s[3])};
      *(u32x2*)&Xl[row][c8] = pk;
    }
    __syncthreads();
    s16x8 wf[2], xf[4];
#pragma unroll
    for (int i = 0; i < 2; ++i)
      wf[i] = *(const s16x8*)&Wl[32 * wy + 16 * i + l16][quad * 8];
#pragma unroll
    for (int j = 0; j < 4; ++j)
      xf[j] = *(const s16x8*)&Xl[64 * wx + 16 * j + l16][quad * 8];
#pragma unroll
    for (int i = 0; i < 2; ++i)
#pragma unroll
      for (int j = 0; j < 4; ++j) acc[i][j] = MFMA32(wf[i], xf[j], acc[i][j]);
  }
#pragma unroll
  for (int i = 0; i < 2; ++i) {
    int cb = c0 + 32 * wy + 16 * i + 4 * quad;
    float4 b4 = *(const float4*)(bo + cb);
    float bb[4] = {b4.x, b4.y, b4.z, b4.w};
#pragma unroll
    for (int j = 0; j < 4; ++j) {
      int tok = t0 + 64 * wx + 16 * j + l16;
      int b = tok >> 12, tokn = tok & 4095;
#pragma unroll
      for (int r = 0; r < 4; ++r)
        out[((size_t)(b * 256 + cb + r)) * 4096 + tokn] = acc[i][j][r] + bb[r];
    }
  }
}

extern "C" void kernel_launch(void* const* d_in, const int* in_sizes, int n_in,
                              void* d_out, int out_size, void* d_ws, size_t ws_size,
                              hipStream_t stream) {
  (void)in_sizes; (void)n_in; (void)out_size; (void)ws_size;
  const float* x = (const float*)d_in[0];
  const float* wq = (const float*)d_in[1];
  const float* bq = (const float*)d_in[2];
  const float* wo = (const float*)d_in[3];
  const float* bo = (const float*)d_in[4];
  float* out = (float*)d_out;
  ushort* ws = (ushort*)d_ws;
  // ws layout:
  ushort* xbf = ws;                    // [8192][256]  (dead after qkv)
  ushort* OF0 = ws;                    // split0 partial O overlays dead xbf
  ushort* QG  = ws + 2097152;          // [2][8][4096][32]
  ushort* KG  = ws + 4194304;
  ushort* VtG = ws + 6291456;          // [2][8][32][4096]
  ushort* wT  = ws + 8388608;          // [768][256]
  ushort* woT = ws + 8585216;          // [256][256]
  ushort* OFb = ws + 8650752;          // split1 partial O: 2,097,152 ushorts
  float* LF = (float*)(ws + 12845056); // [2][16][4096] f32
  prep_kernel<<<576, 256, 0, stream>>>(x, wq, wo, xbf, wT, woT);
  qkv_kernel<<<dim3(64, 12), 256, 0, stream>>>(xbf, wT, bq, QG, KG, VtG);
  attn_split<<<1024, 256, 0, stream>>>(QG, KG, VtG, OF0, OFb, LF);
  proj_split<<<dim3(64, 4), 256, 0, stream>>>(OF0, OFb, LF, woT, bo, out);
}